// Round 2
// baseline (67.151 us; speedup 1.0000x reference)
//
#include <hip/hip_runtime.h>

#define D 256
#define NBLOCKS 1024
#define WAVES_PER_BLOCK 4

__global__ __launch_bounds__(256) void gc_partial(
    const float* __restrict__ feat,
    const int* __restrict__ known,
    const int* __restrict__ unknown,
    float* __restrict__ acc,   // [3*D]: s_all | s_known | s_unknown
    int N)
{
    const int lane = threadIdx.x & 63;
    const int wave = threadIdx.x >> 6;
    const int gw   = blockIdx.x * WAVES_PER_BLOCK + wave;
    const int nw   = gridDim.x * WAVES_PER_BLOCK;

    float4 aAll = {0.f, 0.f, 0.f, 0.f};
    float4 aK   = {0.f, 0.f, 0.f, 0.f};
    float4 aU   = {0.f, 0.f, 0.f, 0.f};

    for (int row = gw; row < N; row += nw) {
        const float4* rp = (const float4*)(feat + (size_t)row * D);
        float4 v = rp[lane];                       // 16B/lane x 64 lanes = full row
        float ss = v.x * v.x + v.y * v.y + v.z * v.z + v.w * v.w;
        #pragma unroll
        for (int off = 32; off > 0; off >>= 1)
            ss += __shfl_xor(ss, off);             // wave64 reduce
        float inv = 1.0f / fmaxf(sqrtf(ss), 1e-8f);
        float4 u = {v.x * inv, v.y * inv, v.z * inv, v.w * inv};

        aAll.x += u.x; aAll.y += u.y; aAll.z += u.z; aAll.w += u.w;
        const bool kn = known[row] != 0;           // int32 masks, wave-uniform
        const bool un = unknown[row] != 0;
        if (kn) { aK.x += u.x; aK.y += u.y; aK.z += u.z; aK.w += u.w; }
        if (un) { aU.x += u.x; aU.y += u.y; aU.z += u.z; aU.w += u.w; }
    }

    // block reduce: each thread owns columns 4*lane..4*lane+3 within its wave
    __shared__ float red[WAVES_PER_BLOCK][D];
    float4 accs[3] = {aAll, aK, aU};
    #pragma unroll
    for (int a = 0; a < 3; ++a) {
        float4 t = accs[a];
        red[wave][lane * 4 + 0] = t.x;
        red[wave][lane * 4 + 1] = t.y;
        red[wave][lane * 4 + 2] = t.z;
        red[wave][lane * 4 + 3] = t.w;
        __syncthreads();
        const int col = threadIdx.x;               // 256 threads = 256 columns
        float s = red[0][col] + red[1][col] + red[2][col] + red[3][col];
        atomicAdd(acc + a * D + col, s);
        __syncthreads();
    }
}

__global__ __launch_bounds__(256) void gc_final(
    const float* __restrict__ acc, float* __restrict__ out, int N)
{
    const int d = threadIdx.x;
    const float sa = acc[d];
    const float sk = acc[D + d];
    const float su = acc[2 * D + d];
    float p1 = sa * sk;   // term1 partial
    float p2 = sk * sk;   // sim_AA partial
    float p3 = sk * su;   // sim_AP partial
    #pragma unroll
    for (int off = 32; off > 0; off >>= 1) {
        p1 += __shfl_xor(p1, off);
        p2 += __shfl_xor(p2, off);
        p3 += __shfl_xor(p3, off);
    }
    __shared__ float r[3][WAVES_PER_BLOCK];
    const int wave = threadIdx.x >> 6, lane = threadIdx.x & 63;
    if (lane == 0) { r[0][wave] = p1; r[1][wave] = p2; r[2][wave] = p3; }
    __syncthreads();
    if (threadIdx.x == 0) {
        float t1 = r[0][0] + r[0][1] + r[0][2] + r[0][3];
        float t2 = r[1][0] + r[1][1] + r[1][2] + r[1][3];
        float t3 = r[2][0] + r[2][1] + r[2][2] + r[2][3];
        // LAMDA=0.5, ETA=1.0 -> gain = t1 - 0.5*t2 - 1.0*t3
        float gain = t1 - 0.5f * t2 - t3;
        out[0] = -gain / (float)N;
    }
}

extern "C" void kernel_launch(void* const* d_in, const int* in_sizes, int n_in,
                              void* d_out, int out_size, void* d_ws, size_t ws_size,
                              hipStream_t stream) {
    const float* feat = (const float*)d_in[0];
    const int* known = (const int*)d_in[1];
    const int* unknown = (const int*)d_in[2];
    const int N = in_sizes[1];                     // mask length = row count
    float* acc = (float*)d_ws;                     // 3*D floats

    hipMemsetAsync(acc, 0, 3 * D * sizeof(float), stream);
    gc_partial<<<NBLOCKS, 256, 0, stream>>>(feat, known, unknown, acc, N);
    gc_final<<<1, 256, 0, stream>>>(acc, (float*)d_out, N);
}